// Round 3
// baseline (503.082 us; speedup 1.0000x reference)
//
#include <hip/hip_runtime.h>
#include <hip/hip_bf16.h>
#include <math.h>

// ---------------------------------------------------------------------------
// QuantumProcessingLayer: out = tanh(concat(f(x), f(x)^2) @ W + b)
//   f(x) = tanh(2pi x) + 0.1*sin(2pi x)*cos(pi x)
// M=16384 (B*S), F=2048, K=4096 (2F), N=2048 (U). fp32 in/out, bf16 MFMA core.
// R6: read/MFMA pipe overlap. Diagnosis: R4/R5 ~50% MfmaUtil == 620cyc MFMA +
//     576cyc ds_read serialized per phase (reads issued after MFMA cluster,
//     exposed at next phase's lgkmcnt(0)). Restructure: 2 phases per k-half,
//     ONE barrier per half-tile; reads issued BEFORE the MFMA cluster and
//     interleaved via sched_group_barrier (CK v3 pattern, DS_READ:MFMA).
//     A(h) = {lgkm0; rd fb4; MFMA fb0}                      (no barrier)
//     B(h) = {lgkm0; vmcnt(4); barrier; stage A&B(h+3);
//             rd (h+1) fb0+bv; MFMA fb4}
//     vmcnt queue (4 gld per B-phase/wave): prologue stages 0,1,2 (12 out),
//     vmcnt(8) lands slot0. Steady B(h): outstanding {h+1,h+2}=8, vmcnt(4)
//     drains h+1 exactly. Tail: B(125) vm4 lands 126; B(126) vm0 lands 127.
//     Slot reuse: stage(h+3)->slot (h-1)&3; last reader drained at B(h-1)
//     entry lgkm0, two barriers (B(h-1),B(h)) before the overwrite issues.
// ---------------------------------------------------------------------------

typedef __bf16 b16x8 __attribute__((ext_vector_type(8)));
typedef float f32x4 __attribute__((ext_vector_type(4)));

constexpr int Mdim = 16384;
constexpr int Fdim = 2048;
constexpr int Kdim = 4096;
constexpr int Ndim = 2048;

// tanh(2*pi*x): e = exp(-4*pi*|x|); t = (1-e)/(1+e) via v_rcp
__device__ __forceinline__ float tanh_2pix(float x) {
  float ax = fabsf(x);
  float e = __expf(-12.566370614359172f * ax);
  float t = (1.0f - e) * __builtin_amdgcn_rcpf(1.0f + e);
  return copysignf(t, x);
}

__device__ __forceinline__ float fast_tanh(float x) {
  float ax = fabsf(x);
  float e = __expf(-2.0f * ax);
  float t = (1.0f - e) * __builtin_amdgcn_rcpf(1.0f + e);
  return copysignf(t, x);
}

// ---------------- prologue: feats[m][k] (bf16), k<F: qe, k>=F: qe^2 ---------
struct __align__(16) B8 { __bf16 v[8]; };

__global__ void feats_kernel(const float* __restrict__ x, __bf16* __restrict__ feats) {
  int idx = blockIdx.x * blockDim.x + threadIdx.x;  // one thread per 8 elems
  long i8 = (long)idx << 3;
  float4 xv0 = reinterpret_cast<const float4*>(x)[idx * 2];
  float4 xv1 = reinterpret_cast<const float4*>(x)[idx * 2 + 1];
  float q[8] = {xv0.x, xv0.y, xv0.z, xv0.w, xv1.x, xv1.y, xv1.z, xv1.w};
  B8 qe, en;
#pragma unroll
  for (int j = 0; j < 8; ++j) {
    float xx = q[j];
    // sin(2*pi*x) = v_sin(x revolutions); cos(pi*x) = v_cos(x/2 revolutions)
    float s = __builtin_amdgcn_sinf(xx);
    float c = __builtin_amdgcn_cosf(0.5f * xx);
    float v = tanh_2pix(xx) + 0.1f * s * c;
    qe.v[j] = (__bf16)v;
    en.v[j] = (__bf16)(v * v);
  }
  int m = (int)(i8 >> 11);     // / Fdim
  int f = (int)(i8 & (Fdim - 1));
  size_t base = (size_t)m * Kdim + f;
  *reinterpret_cast<B8*>(feats + base) = qe;
  *reinterpret_cast<B8*>(feats + base + Fdim) = en;
}

// ---------------- W [K][N] fp32  ->  Wt [N][K] bf16 ------------------------
__global__ void wtrans_kernel(const float* __restrict__ W, __bf16* __restrict__ Wt) {
  __shared__ float tile[32][33];
  int bn = blockIdx.x;   // N/32 = 64
  int bk = blockIdx.y;   // K/32 = 128
  int tx = threadIdx.x;  // 0..31
  int ty = threadIdx.y;  // 0..7
#pragma unroll
  for (int i = 0; i < 4; ++i) {
    int kk = bk * 32 + ty + i * 8;
    tile[ty + i * 8][tx] = W[(size_t)kk * Ndim + bn * 32 + tx];
  }
  __syncthreads();
#pragma unroll
  for (int i = 0; i < 4; ++i) {
    int nn = bn * 32 + ty + i * 8;
    Wt[(size_t)nn * Kdim + bk * 32 + tx] = (__bf16)tile[tx][ty + i * 8];
  }
}

// ---------------- GEMM: out = tanh(A @ Wt^T + b) ---------------------------
typedef const __attribute__((address_space(1))) void* gptr1;
typedef __attribute__((address_space(3))) void* lptr3;

__device__ __forceinline__ void gld_lds16(const __bf16* g, __bf16* l) {
  __builtin_amdgcn_global_load_lds((gptr1)g, (lptr3)l, 16, 0, 0);
}

#define BARRIER()    asm volatile("s_barrier" ::: "memory")
#define WAIT_LGKM0() asm volatile("s_waitcnt lgkmcnt(0)" ::: "memory")
#define WAIT_VM(n)   asm volatile("s_waitcnt vmcnt(" #n ")" ::: "memory")
#define SGB          __builtin_amdgcn_sched_group_barrier

// MFMA cluster: 16 x 16x16x32 on acc rows [FB..FB+3].
#define MFMA16(AV, BV, FB) do {                                               \
    __builtin_amdgcn_s_setprio(1);                                            \
    _Pragma("unroll")                                                         \
    for (int i_ = 0; i_ < 4; ++i_)                                            \
      _Pragma("unroll")                                                       \
      for (int j_ = 0; j_ < 4; ++j_)                                          \
        acc[(FB) + i_][j_] = __builtin_amdgcn_mfma_f32_16x16x32_bf16(         \
            AV[i_], BV[j_], acc[(FB) + i_][j_], 0, 0, 0);                     \
    __builtin_amdgcn_s_setprio(0);                                            \
  } while (0)

// Interleave directives (CK v3 style). Masks per LLVM SchedGroupMask:
// MFMA=0x8, VMEM_READ=0x20, DS_READ=0x100.
#define ILA() do {                                                            \
    _Pragma("unroll")                                                         \
    for (int q_ = 0; q_ < 4; ++q_) { SGB(0x100, 1, 0); SGB(0x008, 4, 0); }    \
  } while (0)
#define ILB() do {                                                            \
    SGB(0x020, 4, 0);                                                         \
    _Pragma("unroll")                                                         \
    for (int q_ = 0; q_ < 4; ++q_) { SGB(0x100, 2, 0); SGB(0x008, 4, 0); }    \
  } while (0)
#define ILB0() do {                                                           \
    _Pragma("unroll")                                                         \
    for (int q_ = 0; q_ < 4; ++q_) { SGB(0x100, 2, 0); SGB(0x008, 4, 0); }    \
  } while (0)

__global__ __launch_bounds__(512, 2) void gemm_tanh_kernel(
    const __bf16* __restrict__ A,    // [M][K] feats
    const __bf16* __restrict__ Bt,   // [N][K] W^T
    const float* __restrict__ bias,  // [N]
    float* __restrict__ out) {       // [M][N]
  // 128 KiB: A slots [4][256 rows][32 k] then B slots [4][256][32]
  __shared__ __align__(16) __bf16 smem[65536];
  __bf16* const sA = smem;           // 4 x 8192 elems
  __bf16* const sB = smem + 32768;   // 4 x 8192 elems

  const int tid = threadIdx.x;
  const int wv = tid >> 6;
  const int lane = tid & 63;

  // T1: XCD-aware bijective swizzle (nwg=512, 512%8==0).
  const int orig = blockIdx.y * 8 + blockIdx.x;
  const int wg = (orig & 7) * 64 + (orig >> 3);
  const int m0 = (wg >> 3) * 256;
  const int n0 = (wg & 7) * 256;

  const int wm = (wv >> 2) * 128;  // 2 M-waves
  const int wn = (wv & 3) * 64;    // 4 N-waves
  const int lr = lane & 15;
  const int lq = lane >> 4;

  // ---- staging: half-tile slot = 256 rows x 32 k = 16 KB. LDS dest linear;
  // global source chunk pre-swizzled so the read-side XOR pattern (0 bank
  // conflicts R2-R5, measured) sees its data.
  const int L0 = wv * 128 + lane;
  const int L1 = L0 + 64;
  const int r0 = L0 >> 2, r1 = L1 >> 2;
  const int c0 = (L0 & 3) ^ ((r0 >> 1) & 3);
  const int c1 = (L1 & 3) ^ ((r1 >> 1) & 3);
  const __bf16* gA0 = A + (size_t)(m0 + r0) * Kdim + c0 * 8;
  const __bf16* gA1 = A + (size_t)(m0 + r1) * Kdim + c1 * 8;
  const __bf16* gB0 = Bt + (size_t)(n0 + r0) * Kdim + c0 * 8;
  const __bf16* gB1 = Bt + (size_t)(n0 + r1) * Kdim + c1 * 8;
  const int d0 = wv * 1024;        // wave-uniform LDS dest (HW adds lane*16B)
  const int d1 = d0 + 512;

  auto stageAB = [&](int h) {   // 4 gld: both operands' half-tile h
    __bf16* a = sA + (h & 3) * 8192;
    __bf16* b = sB + (h & 3) * 8192;
    gld_lds16(gA0 + h * 32, a + d0);
    gld_lds16(gA1 + h * 32, a + d1);
    gld_lds16(gB0 + h * 32, b + d0);
    gld_lds16(gB1 + h * 32, b + d1);
  };

  // ---- fragment reads (swizzled chunk; 0 conflicts measured) --------------
  const int chunk = (lq ^ ((lr >> 1) & 3)) * 8;
  const int ard = (wm + lr) * 32 + chunk;
  const int brd = (wn + lr) * 32 + chunk;

  f32x4 acc[8][4];
#pragma unroll
  for (int i = 0; i < 8; ++i)
#pragma unroll
    for (int j = 0; j < 4; ++j) acc[i][j] = (f32x4){0.f, 0.f, 0.f, 0.f};

  // named frag buffers (static indexing only -- rule #20)
  b16x8 av0[4], av1[4], bvE[4], bvO[4];
  auto rdA = [&](b16x8 (&dst)[4], int slot, int fb) {
#pragma unroll
    for (int i = 0; i < 4; ++i)
      dst[i] = *reinterpret_cast<const b16x8*>(sA + slot * 8192 + ard + (fb + i) * 512);
  };
  auto rdB = [&](b16x8 (&dst)[4], int slot) {
#pragma unroll
    for (int i = 0; i < 4; ++i)
      dst[i] = *reinterpret_cast<const b16x8*>(sB + slot * 8192 + brd + i * 512);
  };

  // Bias loaded & drained BEFORE staging (keeps the vmcnt queue exact).
  float bval[4];
#pragma unroll
  for (int j = 0; j < 4; ++j) bval[j] = bias[n0 + wn + j * 16 + lr];
  WAIT_VM(0);

  // ---- prologue: stage slots 0,1,2 (12 gld); land slot 0 ------------------
  stageAB(0); stageAB(1); stageAB(2);
  WAIT_VM(8);            // slot 0 landed; {1,2} in flight
  BARRIER();
  rdA(av0, 0, 0); rdB(bvE, 0);

  // ---- main loop: 62 iterations x 2 half-tiles (h = 0..123) ---------------
  for (int t = 0; t < 62; ++t) {
    const int h = 2 * t;
    const int s0 = h & 3, s1 = (h + 1) & 3, s2 = (h + 2) & 3;
    // A(h) even
    WAIT_LGKM0();
    rdA(av1, s0, 4);
    MFMA16(av0, bvE, 0);
    ILA();
    // B(h)
    WAIT_LGKM0(); WAIT_VM(4);
    BARRIER();
    stageAB(h + 3);
    rdA(av0, s1, 0); rdB(bvO, s1);
    MFMA16(av1, bvE, 4);
    ILB();
    // A(h+1) odd
    WAIT_LGKM0();
    rdA(av1, s1, 4);
    MFMA16(av0, bvO, 0);
    ILA();
    // B(h+1)
    WAIT_LGKM0(); WAIT_VM(4);
    BARRIER();
    stageAB(h + 4);
    rdA(av0, s2, 0); rdB(bvE, s2);
    MFMA16(av1, bvO, 4);
    ILB();
  }

  // ---- tail: h = 124 (stage 127), 125, 126, 127 ---------------------------
  // h=124 (even, slot 0)
  WAIT_LGKM0();
  rdA(av1, 0, 4);
  MFMA16(av0, bvE, 0);
  ILA();
  WAIT_LGKM0(); WAIT_VM(4);   // drains stage(125)
  BARRIER();
  stageAB(127);
  rdA(av0, 1, 0); rdB(bvO, 1);
  MFMA16(av1, bvE, 4);
  ILB();
  // h=125 (odd, slot 1)
  WAIT_LGKM0();
  rdA(av1, 1, 4);
  MFMA16(av0, bvO, 0);
  ILA();
  WAIT_LGKM0(); WAIT_VM(4);   // outstanding {126,127}=8 -> drains 126
  BARRIER();
  rdA(av0, 2, 0); rdB(bvE, 2);
  MFMA16(av1, bvO, 4);
  ILB0();
  // h=126 (even, slot 2)
  WAIT_LGKM0();
  rdA(av1, 2, 4);
  MFMA16(av0, bvE, 0);
  ILA();
  WAIT_LGKM0(); WAIT_VM(0);   // drain stage(127)
  BARRIER();
  rdA(av0, 3, 0); rdB(bvO, 3);
  MFMA16(av1, bvE, 4);
  ILB0();
  // h=127 (odd, slot 3)
  WAIT_LGKM0();
  rdA(av1, 3, 4);
  MFMA16(av0, bvO, 0);
  ILA();
  WAIT_LGKM0();
  MFMA16(av1, bvO, 4);

  // ---- epilogue: C/D layout col=lane&15, row=(lane>>4)*4+reg --------------
#pragma unroll
  for (int j = 0; j < 4; ++j) {
    const int gn = n0 + wn + j * 16 + lr;
#pragma unroll
    for (int i = 0; i < 8; ++i) {
      const int gm = m0 + wm + i * 16 + lq * 4;
#pragma unroll
      for (int r = 0; r < 4; ++r) {
        float v = acc[i][j][r] + bval[j];
        out[(size_t)(gm + r) * Ndim + gn] = fast_tanh(v);
      }
    }
  }
}

// ---------------------------------------------------------------------------
extern "C" void kernel_launch(void* const* d_in, const int* in_sizes, int n_in,
                              void* d_out, int out_size, void* d_ws, size_t ws_size,
                              hipStream_t stream) {
  const float* x = (const float*)d_in[0];
  const float* W = (const float*)d_in[1];
  const float* b = (const float*)d_in[2];
  float* out = (float*)d_out;

  // ws layout: Wt bf16 [N*K] (16.8 MB) | feats bf16 [M*K] (134 MB)
  __bf16* Wt = (__bf16*)d_ws;
  __bf16* feats = Wt + (size_t)Ndim * Kdim;

  hipLaunchKernelGGL(feats_kernel, dim3(Mdim * Fdim / 8 / 256), dim3(256), 0,
                     stream, x, feats);
  hipLaunchKernelGGL(wtrans_kernel, dim3(Ndim / 32, Kdim / 32), dim3(32, 8), 0,
                     stream, W, Wt);
  hipLaunchKernelGGL(gemm_tanh_kernel, dim3(Ndim / 256, Mdim / 256), dim3(512),
                     0, stream, feats, Wt, b, out);
}